// Round 1
// 408.564 us; speedup vs baseline: 1.0581x; 1.0581x over previous
//
#include <hip/hip_runtime.h>
#include <hip/hip_bf16.h>

typedef __attribute__((ext_vector_type(8))) short short8;
typedef __attribute__((ext_vector_type(4))) short short4v;
typedef __attribute__((ext_vector_type(4))) float f32x4;
typedef unsigned short u16;

// ---- bf16 helpers (bit-level, RNE) ----
__device__ inline float b2f(u16 u) {
    unsigned int i = ((unsigned int)u) << 16;
    float f; __builtin_memcpy(&f, &i, 4); return f;
}
__device__ inline u16 f2b(float f) {
    unsigned int i; __builtin_memcpy(&i, &f, 4);
    unsigned int r = (i + 0x7FFFu + ((i >> 16) & 1u)) >> 16;
    return (u16)r;
}

// Cross-half (lane ^ 32) sum via v_permlane32_swap_b32 — pure VALU, no lgkm.
// With a=b=x the swap yields lo'=[x_lo|x_lo], hi'=[x_hi|x_hi]; lo'+hi' is the
// cross-half sum broadcast to all 64 lanes. Bit-identical to pr+shfl_xor(pr,32)
// (float add is commutative). Avoids ds_bpermute, whose lgkmcnt wait drains the
// in-flight ds_read_b128 S-prefetches (DS queue is in-order) every scan step.
__device__ inline float xsum32(float x) {
    unsigned u; __builtin_memcpy(&u, &x, 4);
    auto r = __builtin_amdgcn_permlane32_swap(u, u, false, false);
    unsigned s0 = r[0], s1 = r[1];
    float f0, f1; __builtin_memcpy(&f0, &s0, 4); __builtin_memcpy(&f1, &s1, 4);
    return f0 + f1;
}

#define GLDS(g, l) __builtin_amdgcn_global_load_lds( \
    (const __attribute__((address_space(1))) void*)(g), \
    (__attribute__((address_space(3))) void*)(l), 16, 0, 0)

// ============================================================
// Phase 0: fp32 -> bf16 conversion (4 elements / thread)
// ============================================================
__global__ __launch_bounds__(256) void cvt_k(const float* __restrict__ src,
                                             u16* __restrict__ dst, int n4)
{
    const int i = blockIdx.x * blockDim.x + threadIdx.x;
    if (i < n4) {
        const f32x4 v = ((const f32x4*)src)[i];
        short4v o;
        o.x = (short)f2b(v.x); o.y = (short)f2b(v.y);
        o.z = (short)f2b(v.z); o.w = (short)f2b(v.w);
        ((short4v*)dst)[i] = o;
    }
}

// ============================================================
// Phase 0b: V0 transpose  V0T[b][j][n] = V0[b][n][j]  (fp32, 1 MB)
// 64 blocks x 256 thr; thread = (b, j, n-chunk of 16)
// ============================================================
__global__ __launch_bounds__(256) void vT_k(const float* __restrict__ V0,
                                            float* __restrict__ V0T)
{
    const int gid = blockIdx.x * 256 + threadIdx.x;   // 0..16383
    const int b = gid >> 9, j = (gid >> 6) & 7, n0 = (gid & 63) * 16;
    const float* src = V0 + (long)b * 8192 + (long)n0 * 8 + j;
    float* dst = V0T + (long)b * 8192 + (long)j * 1024 + n0;
#pragma unroll
    for (int i = 0; i < 16; i += 4) {
        f32x4 o = { src[(i + 0) * 8], src[(i + 1) * 8],
                    src[(i + 2) * 8], src[(i + 3) * 8] };
        *(f32x4*)(dst + i) = o;
    }
}

// ============================================================
// Phase 1a: fused GEMM  C = X · W^T, XOR-swizzled LDS (bank-conflict-free)
// X: [16384, 1024]; W: [3072, 1024] (3 stacked); out: 3 x [16384, 1024]
// Tiles: BM=128, BN=128, BK=64; 256 threads = 4 waves (2x2 of 64x64)
// LDS layout: row r (stride 64 elems = 128 B); within row, physical 16B
// block p holds global col-block p ^ (r&7).
// ============================================================
__global__ __launch_bounds__(256) void gemm_kvq(
    const u16* __restrict__ X, const u16* __restrict__ Wbf,
    u16* __restrict__ Ko, u16* __restrict__ Vo, u16* __restrict__ Qo)
{
    __shared__ u16 As[128 * 64];
    __shared__ u16 Bs[128 * 64];

    const int bm = blockIdx.x;            // 0..127  (M tiles)
    const int bn = blockIdx.y;            // 0..23   (N tiles over 3072)
    const int widx = bn >> 3;
    const int n0 = (bn & 7) * 128;
    const u16* W = Wbf + (long)widx * 1048576;
    u16* O = (widx == 0) ? Ko : (widx == 1 ? Vo : Qo);

    const int tid = threadIdx.x;
    const int wave = tid >> 6;
    const int lane = tid & 63;

    const int srow = lane >> 3;                     // 0..7 row within 1KB chunk
    const int scol = ((lane & 7) ^ srow) * 8;       // swizzled source col block

    const int wm = (wave & 1) * 64;
    const int wn = (wave >> 1) * 64;
    const int qd = lane >> 4;
    const int ln = lane & 15;
    const int lx = ln & 7;                          // row&7 for swizzle

    f32x4 acc[4][4];
#pragma unroll
    for (int i = 0; i < 4; i++)
#pragma unroll
        for (int j = 0; j < 4; j++) acc[i][j] = (f32x4){0.f, 0.f, 0.f, 0.f};

    for (int k0 = 0; k0 < 1024; k0 += 64) {
        __syncthreads();  // prev-iter LDS reads done
#pragma unroll
        for (int c = 0; c < 4; c++) {
            const int chunk = wave * 4 + c;      // 0..15, 1KB each
            const int row = chunk * 8 + srow;    // tile row 0..127
            const u16* ga = X + (long)(bm * 128 + row) * 1024 + k0 + scol;
            GLDS(ga, &As[chunk * 512]);
            const u16* gb = W + (long)(n0 + row) * 1024 + k0 + scol;
            GLDS(gb, &Bs[chunk * 512]);
        }
        __syncthreads();  // drains vmcnt -> staged data visible
#pragma unroll
        for (int kk = 0; kk < 2; kk++) {
            short8 af[4], bf[4];
#pragma unroll
            for (int mt = 0; mt < 4; mt++)
                af[mt] = *(const short8*)&As[(wm + mt * 16 + ln) * 64 +
                                             (((kk * 4 + qd) ^ lx) * 8)];
#pragma unroll
            for (int nt = 0; nt < 4; nt++)
                bf[nt] = *(const short8*)&Bs[(wn + nt * 16 + ln) * 64 +
                                             (((kk * 4 + qd) ^ lx) * 8)];
#pragma unroll
            for (int mt = 0; mt < 4; mt++)
#pragma unroll
                for (int nt = 0; nt < 4; nt++)
                    acc[mt][nt] = __builtin_amdgcn_mfma_f32_16x16x32_bf16(
                        af[mt], bf[nt], acc[mt][nt], 0, 0, 0);
        }
    }

    // epilogue: C/D layout col=lane&15, row=quad*4+reg (verified m89/m91)
#pragma unroll
    for (int mt = 0; mt < 4; mt++) {
#pragma unroll
        for (int nt = 0; nt < 4; nt++) {
            const int r0 = bm * 128 + wm + mt * 16 + qd * 4;
            const int c = n0 + wn + nt * 16 + ln;
#pragma unroll
            for (int r = 0; r < 4; r++)
                O[(long)(r0 + r) * 1024 + c] = f2b(acc[mt][nt][r]);
        }
    }
}

// ============================================================
// Phase 1c: per-row scalars, 4 t's per block.
//   S[b][t][0..7]  = 0.5 * Vtk_u * rn      (prescaled for W=2U form)
//   S[b][t][8..15] = 2.0 * k_r_u * rn
//   S[b][t][16..23]= 0.5 * Vtq
// All scalings are powers of two -> bit-exact vs unscaled recurrence.
// Block = (b, t-group of 4); thread = (j = tid&7, c = tid>>3), n = c*32..+31
// K,Q bf16 (contiguous b128); V0T, Wkr fp32 (contiguous f32x4, L2-resident)
// ============================================================
__global__ __launch_bounds__(256) void scal_k(
    const u16* __restrict__ K, const u16* __restrict__ Q,
    const float* __restrict__ V0T, const float* __restrict__ Wkr,
    float* __restrict__ S)
{
    const int b  = blockIdx.x & 31;
    const int t0 = (blockIdx.x >> 5) * 4;
    const int tid = threadIdx.x;
    const int j = tid & 7, c = tid >> 3;      // c: 0..31
    const int n0 = c * 32;

    f32x4 vv[8], ww[8];
    {
        const f32x4* vp = (const f32x4*)(V0T + (long)b * 8192 + (long)j * 1024 + n0);
        const f32x4* wp = (const f32x4*)(Wkr + (long)j * 1024 + n0);
#pragma unroll
        for (int i = 0; i < 8; i++) { vv[i] = vp[i]; ww[i] = wp[i]; }
    }

    float avk[4], akr[4], avq[4], ass[4];
#pragma unroll
    for (int dt = 0; dt < 4; dt++) { avk[dt] = akr[dt] = avq[dt] = ass[dt] = 0.f; }

#pragma unroll
    for (int dt = 0; dt < 4; dt++) {
        const long m = (long)(t0 + dt) * 32 + b;
        const short8* kp = (const short8*)(K + m * 1024 + n0);
        const short8* qp = (const short8*)(Q + m * 1024 + n0);
#pragma unroll
        for (int i = 0; i < 4; i++) {
            const short8 kb = kp[i], qb = qp[i];
#pragma unroll
            for (int e = 0; e < 8; e++) {
                const int idx = i * 8 + e;
                const float kv = b2f((u16)kb[e]);
                const float qv = b2f((u16)qb[e]);
                const float vj = vv[idx >> 2][idx & 3];
                const float wj = ww[idx >> 2][idx & 3];
                avk[dt] = fmaf(vj, kv, avk[dt]);
                akr[dt] = fmaf(wj, kv, akr[dt]);
                avq[dt] = fmaf(vj, qv, avq[dt]);
                ass[dt] = fmaf(kv, kv, ass[dt]);
            }
        }
    }

    __shared__ float red[4][4][3][8];   // [wave][dt][v][j]
    __shared__ float ssr[4][4];         // [wave][dt]
    const int wave = tid >> 6, lane = tid & 63;
#pragma unroll
    for (int dt = 0; dt < 4; dt++) {
        float a = avk[dt], k2 = akr[dt], q = avq[dt], s = ass[dt];
#pragma unroll
        for (int off = 8; off < 64; off <<= 1) {
            a  += __shfl_xor(a,  off, 64);
            k2 += __shfl_xor(k2, off, 64);
            q  += __shfl_xor(q,  off, 64);
            s  += __shfl_xor(s,  off, 64);
        }
        if (lane < 8) {
            red[wave][dt][0][lane] = a;
            red[wave][dt][1][lane] = k2;
            red[wave][dt][2][lane] = q;
        }
        if (lane == 0) ssr[wave][dt] = s;
    }
    __syncthreads();
    if (tid < 128) {
        const int dt = tid >> 5, rr = tid & 31;
        if (rr < 24) {
            const int v = rr >> 3, jj = rr & 7;
            float s = red[0][dt][v][jj] + red[1][dt][v][jj] +
                      red[2][dt][v][jj] + red[3][dt][v][jj];
            if (v != 2) {
                const float n2 = ssr[0][dt] + ssr[1][dt] + ssr[2][dt] + ssr[3][dt];
                const float inv = 1.0f / (sqrtf(n2) + 1e-6f);
                s *= (v == 0) ? (0.5f * inv) : (2.0f * inv);
            } else {
                s *= 0.5f;
            }
            S[((long)b * 512 + t0 + dt) * 32 + v * 8 + jj] = s;
        }
    }
}

// ============================================================
// Phase 2: the scan, r-split x2. Thread = (b, n, r-half); W[4] each where
// W = 2*U (prescaled S makes this bit-exact and drops one v_mul from the
// serial exp chain: exp(2x) = exp(fma(delta, 2*kr, W))).
// Cross-half (lane^32) dot-product exchange via v_permlane32_swap (VALU) —
// NOT ds_bpermute, which shares lgkmcnt with the in-order DS queue and was
// draining the per-step ds_read_b128 S-prefetches (~2x120cy on the serial
// chain every step).
// 512 blocks x 128 thr -> 4 waves/CU; S[b] in LDS (64KB), depth-2
// register pipeline on S; 16-step-deep global prefetch on V.
// ============================================================
__global__ __launch_bounds__(128) void scan_k(
    const u16* __restrict__ Vbuf, const float* __restrict__ S,
    const float* __restrict__ U0, float* __restrict__ outp,
    float* __restrict__ Ufin)
{
    __shared__ float Sl[512 * 32];  // 64 KB

    const int b = blockIdx.x >> 4;
    const int chunk = blockIdx.x & 15;          // n-chunk of 64
    const int wave = threadIdx.x >> 6, lane = threadIdx.x & 63;
    const int rh = lane >> 5;                   // r-half (0: r0..3, 1: r4..7)
    const int n = chunk * 64 + wave * 32 + (lane & 31);
    const int so = rh * 4;

    // stage S[b] (coalesced, contiguous 64KB)
    {
        const f32x4* Sg = (const f32x4*)(S + (long)b * 16384);
        f32x4* Sd = (f32x4*)Sl;
        for (int i = threadIdx.x; i < 4096; i += 128) Sd[i] = Sg[i];
    }

    float U[4];   // holds W = 2*U
    {
        const float* u0 = U0 + ((long)b * 1024 + n) * 8 + so;
#pragma unroll
        for (int j2 = 0; j2 < 4; j2++) U[j2] = 2.0f * u0[j2];
    }

    const u16* vp0 = Vbuf + (long)b * 1024 + n;
    u16 vnx[16];
#pragma unroll
    for (int i = 0; i < 16; i++) vnx[i] = vp0[(long)i * 32768];

    __syncthreads();  // S staged

    f32x4 sc[3], sn[3];
#pragma unroll
    for (int r = 0; r < 3; r++) sc[r] = *(const f32x4*)&Sl[r * 8 + so];
#pragma unroll
    for (int r = 0; r < 3; r++) sn[r] = *(const f32x4*)&Sl[32 + r * 8 + so];

    float* op = outp + (long)b * 1024 + n;

    for (int t0 = 0; t0 < 512; t0 += 16) {
        float vcur[16];
#pragma unroll
        for (int i = 0; i < 16; i++) vcur[i] = b2f(vnx[i]);
        const int tn = (t0 + 16 < 512) ? (t0 + 16) : t0;
#pragma unroll
        for (int i = 0; i < 16; i++) vnx[i] = vp0[(long)(tn + i) * 32768];

#pragma unroll
        for (int i = 0; i < 16; i++) {
            const int t = t0 + i;
            const int tf = (t + 2 < 512) ? (t + 2) : t;
            f32x4 sm[3];
#pragma unroll
            for (int r = 0; r < 3; r++) sm[r] = *(const f32x4*)&Sl[tf * 32 + r * 8 + so];

            const f32x4 a = sc[0], Kk = sc[1], Qq = sc[2];
#pragma unroll
            for (int r = 0; r < 3; r++) { sc[r] = sn[r]; sn[r] = sm[r]; }

            // retrieved: tree + cross-half exchange (a holds 0.5*Vtk*rn, U holds 2u)
            float pr = fmaf(U[0], a.x, U[1] * a.y) + fmaf(U[2], a.z, U[3] * a.w);
            const float ret = xsum32(pr);
            const float delta = vcur[i] - ret;

            const float kr4[4] = {Kk.x, Kk.y, Kk.z, Kk.w};   // 2*kr*rn
            const float vq4[4] = {Qq.x, Qq.y, Qq.z, Qq.w};   // 0.5*Vtq

            float sq0 = 0.f, sq1 = 0.f;
#pragma unroll
            for (int j2 = 0; j2 < 4; j2++) {
                const float xx = fmaf(delta, kr4[j2], U[j2]);                    // = 2x
                const float e = __expf(xx);                                      // exp(2x)
                const float rc = __builtin_amdgcn_rcpf(e + 1.0f);
                const float u = fmaf(-4.0f, rc, 2.0f);                           // 2*tanh(x)
                U[j2] = u;
                if (j2 & 1) sq1 = fmaf(u, vq4[j2], sq1);
                else        sq0 = fmaf(u, vq4[j2], sq0);
            }
            const float Sq = xsum32(sq0 + sq1);
            const float sg = __builtin_amdgcn_rcpf(1.0f + __expf(-Sq));
            const float o = Sq * Sq * sg;  // Sq * silu(Sq)
            if (rh == 0) op[(long)t * 32768] = o;
        }
    }

    // U_final: each thread stores its 4 (16B aligned); undo W=2U scaling
    *(f32x4*)(Ufin + ((long)b * 1024 + n) * 8 + so) =
        (f32x4){0.5f * U[0], 0.5f * U[1], 0.5f * U[2], 0.5f * U[3]};
}

// ============================================================
// V output = V0 (unchanged); 16B-wide fp32 copy (262144 floats)
// ============================================================
__global__ __launch_bounds__(256) void vcopy_k(const float* __restrict__ src,
                                               float* __restrict__ dst)
{
    const int i = blockIdx.x * blockDim.x + threadIdx.x;  // 0..65535
    ((f32x4*)dst)[i] = ((const f32x4*)src)[i];
}

// ============================================================
extern "C" void kernel_launch(void* const* d_in, const int* in_sizes, int n_in,
                              void* d_out, int out_size, void* d_ws, size_t ws_size,
                              hipStream_t stream)
{
    const float* x   = (const float*)d_in[0];   // [512,32,1024]
    const float* Wk  = (const float*)d_in[1];   // [1024,1024]
    const float* Wv  = (const float*)d_in[2];
    const float* Wq  = (const float*)d_in[3];
    const float* Wkr = (const float*)d_in[4];   // [8,1024]
    const float* U0  = (const float*)d_in[5];   // [32,1024,8]
    const float* V0  = (const float*)d_in[6];   // [32,1024,8]
    float* out = (float*)d_out;                 // output(16777216) + U_final(262144) + V(262144)

    char* ws = (char*)d_ws;
    u16*   Xbf = (u16*)(ws);                    // 33,554,432 B
    u16*   Wbf = (u16*)(ws + 33554432);         //  6,291,456 B (Wk|Wv|Wq stacked)
    u16*   Kb  = (u16*)(ws + 39845888);         // 33,554,432 B
    u16*   Vb  = (u16*)(ws + 73400320);         // 33,554,432 B
    u16*   Qb  = (u16*)(ws + 106954752);        // 33,554,432 B
    float* Sc  = (float*)(ws + 140509184);      //  2,097,152 B  (32 x 512 x 32 f32)
    float* V0T = (float*)(ws + 142606336);      //  1,048,576 B  (32 x 8 x 1024 f32)

    cvt_k<<<16384, 256, 0, stream>>>(x,  Xbf,               4194304);
    cvt_k<<<1024,  256, 0, stream>>>(Wk, Wbf,                262144);
    cvt_k<<<1024,  256, 0, stream>>>(Wv, Wbf + 1048576,      262144);
    cvt_k<<<1024,  256, 0, stream>>>(Wq, Wbf + 2097152,      262144);
    vT_k <<<64,    256, 0, stream>>>(V0, V0T);

    gemm_kvq<<<dim3(128, 24), 256, 0, stream>>>(Xbf, Wbf, Kb, Vb, Qb);
    scal_k  <<<4096, 256, 0, stream>>>(Kb, Qb, V0T, Wkr, Sc);
    scan_k  <<<512, 128, 0, stream>>>(Vb, Sc, U0, out, out + 16777216);
    vcopy_k <<<256, 256, 0, stream>>>(V0, out + 17039360);
}